// Round 2
// baseline (533.946 us; speedup 1.0000x reference)
//
#include <hip/hip_runtime.h>
#include <math.h>

#define P_N 4096
#define T_N 128
#define A_N 32
#define K_N 409          // int(4096 * 0.1)
#define TEMP_C 0.5f
#define MOM_C 0.1f
#define MIN_STD_C 0.05f
#define INF_F 1e30f

#define NBLK 256         // grid: 16 particles per block
#define NTHR 512         // 8 waves per block
#define NW   8
#define HSTRIDE 257      // per-wave histogram stride (bank-spread)
#define MAGIC_A 0x9E3779B1u   // "dtw done" token (must differ from poison)
#define MAGIC_B 0xC2B2AE35u   // "select done" token
#define SCOPE_AGT __HIP_MEMORY_SCOPE_AGENT

// native vector type (Clang ext_vector) — required by __builtin_nontemporal_load
typedef float vfloat4 __attribute__((ext_vector_type(4)));

// DPP move: returns src shifted per ctrl; lanes with invalid source get `oldv`.
// ctrl: 0x110+N row_shr:N, 0x142 row_bcast:15, 0x138 wave_shr:1
#define DPPMOV(dst, src, ctrl, oldv)                                          \
  {                                                                           \
    union { float f; int i; } _a, _b, _r;                                     \
    _a.f = (src); _b.f = (oldv);                                              \
    _r.i = __builtin_amdgcn_update_dpp(_b.i, _a.i, (ctrl), 0xF, 0xF, false);  \
    (dst) = _r.f;                                                             \
  }

// LDS is phase-exclusive: select (block 255) vs stats (blocks 0..127).
union Shm {
  struct {                                   // select phase: ~27 KB
    unsigned int skey[P_N];                  // 16 KB
    unsigned int histw[NW * HSTRIDE];        // 8.2 KB per-wave histograms
    float elite_d[K_N];
    int eqbuf[256];
    float wsum[NW];
  } sel;
  struct {                                   // stats phase: ~7.4 KB
    int   sidx[K_N];
    float swn[K_N];
    float sM[16][32];
    float sQ[16][32];
  } st;
};

// ---------------------------------------------------------------------------
// Single fused kernel.
// Phase 1 (all 256 blocks): DTW min-plus DP, 2 particles/wave, DPP scan.
// Handshake: done[bid]=MAGIC_A (release). Block 255 waits for all 256 words,
// runs select, then flips all words to MAGIC_B. Blocks 0..127 wait for
// MAGIC_B on their own word (which THEY overwrote with MAGIC_A this launch,
// so stale MAGIC_B from a previous iteration cannot leak through), then run
// per-t stats. Self-resetting: correct with or without workspace re-poison.
// Deadlock-free by construction: every wait is on an unconditional write and
// all 256 blocks are co-resident (8 waves, <=256 VGPR, 27 KB LDS -> >=1
// block/CU -> capacity >= 256).
// ---------------------------------------------------------------------------
__global__ __launch_bounds__(NTHR, 2) void fused_kernel(
    const float* __restrict__ obs, const float* __restrict__ means,
    const float* __restrict__ stds, const float* __restrict__ noise,
    float* __restrict__ dists, int* __restrict__ elite_idx,
    float* __restrict__ elite_wn, float* __restrict__ meta,
    unsigned int* __restrict__ done, float* __restrict__ out) {
  __shared__ Shm shm;
  __shared__ unsigned int sc_prefix, sc_minkey, sc_maxkey;
  __shared__ int sc_r, sc_cntlt, sc_cnteq;
  __shared__ float sS, sS2;

  const int bid  = blockIdx.x;
  const int tid  = threadIdx.x;
  const int wave = tid >> 6;
  const int lane = tid & 63;

  // ========== phase 1: DTW (identical math to the verified 3-kernel ver) ==========
  {
    const int half = lane >> 5;
    const int l    = lane & 31;
    const int p    = bid * 16 + wave * 2 + half;   // particle id
    const bool is0 = (l == 0);

    const vfloat4* row = (const vfloat4*)(obs + (size_t)p * (T_N * T_N)) + l;

    float P1 = INF_F, P2 = INF_F, P3 = INF_F, P4 = INF_F;
    float p0 = is0 ? 0.0f : INF_F;

    vfloat4 cb[8];
    #pragma unroll
    for (int u = 0; u < 8; ++u) cb[u] = __builtin_nontemporal_load(row + u * 32);

    for (int rb = 0; rb < T_N; rb += 8) {
      const bool pf = (rb + 8 < T_N);
      #pragma unroll
      for (int u = 0; u < 8; ++u) {
        vfloat4 c = cb[u];
        if (pf) cb[u] = __builtin_nontemporal_load(row + (rb + u + 8) * 32);

        float a1 = fminf(P1, p0);
        float a2 = fminf(P2, P1);
        float a3 = fminf(P3, P2);
        float a4 = fminf(P4, P3);

        float B = a1 + c.x;
        B = fminf(B + c.y, a2 + c.y);
        B = fminf(B + c.z, a3 + c.z);
        B = fminf(B + c.w, a4 + c.w);
        float C = (c.x + c.y) + (c.z + c.w);

        float Bp, Cp;
        DPPMOV(Bp, B, 0x111, INF_F); DPPMOV(Cp, C, 0x111, 0.0f);
        B = fminf(Bp + C, B); C = Cp + C;
        DPPMOV(Bp, B, 0x112, INF_F); DPPMOV(Cp, C, 0x112, 0.0f);
        B = fminf(Bp + C, B); C = Cp + C;
        DPPMOV(Bp, B, 0x114, INF_F); DPPMOV(Cp, C, 0x114, 0.0f);
        B = fminf(Bp + C, B); C = Cp + C;
        DPPMOV(Bp, B, 0x118, INF_F); DPPMOV(Cp, C, 0x118, 0.0f);
        B = fminf(Bp + C, B); C = Cp + C;
        DPPMOV(Bp, B, 0x142, INF_F); DPPMOV(Cp, C, 0x142, 0.0f);
        B = fminf(Bp + C, B); C = Cp + C;

        float x;
        DPPMOV(x, B, 0x138, INF_F);
        x = is0 ? INF_F : x;

        float n1 = fminf(a1, x)  + c.x;
        float n2 = fminf(a2, n1) + c.y;
        float n3 = fminf(a3, n2) + c.z;
        float n4 = fminf(a4, n3) + c.w;

        p0 = x; P1 = n1; P2 = n2; P3 = n3; P4 = n4;
      }
    }
    if (l == 31) dists[p] = P4;
  }

  // release: flush dist stores, then post done token
  __threadfence();
  __syncthreads();
  if (tid == 0)
    __hip_atomic_store(&done[bid], MAGIC_A, __ATOMIC_RELEASE, SCOPE_AGT);

  // ========== phase 2: select (block NBLK-1 only) ==========
  if (bid == NBLK - 1) {
    if (tid < NBLK) {
      while (__hip_atomic_load(&done[tid], __ATOMIC_ACQUIRE, SCOPE_AGT) != MAGIC_A)
        __builtin_amdgcn_s_sleep(8);
    }
    __syncthreads();
    __threadfence();   // acquire: invalidate caches before reading dists

    if (tid == 0) { sc_minkey = 0xFFFFFFFFu; sc_maxkey = 0u;
                    sc_cntlt = 0; sc_cnteq = 0; sc_prefix = 0u; sc_r = K_N - 1; }
    __syncthreads();

    // stage keys to LDS + min/max reduce (coherent loads)
    unsigned int localmin = 0xFFFFFFFFu, localmax = 0u;
    for (int p = tid; p < P_N; p += NTHR) {
      float dv = __hip_atomic_load(&dists[p], __ATOMIC_RELAXED, SCOPE_AGT);
      unsigned int k = __float_as_uint(dv);
      shm.sel.skey[p] = k;
      if (k < localmin) localmin = k;
      if (k > localmax) localmax = k;
    }
    #pragma unroll
    for (int d = 32; d > 0; d >>= 1) {
      unsigned int o = __shfl_xor(localmin, (unsigned)d, 64);
      if (o < localmin) localmin = o;
      unsigned int o2 = __shfl_xor(localmax, (unsigned)d, 64);
      if (o2 > localmax) localmax = o2;
    }
    if (lane == 0) { atomicMin(&sc_minkey, localmin); atomicMax(&sc_maxkey, localmax); }
    __syncthreads();
    const unsigned int mn = sc_minkey, mx = sc_maxkey;

    // radix select, MSB-first. Leading bytes where min==max are shared by
    // ALL keys (integer monotonicity) -> skip those passes outright.
    unsigned int mask = 0;
    bool skipping = true;
    for (int shift = 24; shift >= 0; shift -= 8) {
      const unsigned int bmin = (mn >> shift) & 255u;
      const unsigned int bmax = (mx >> shift) & 255u;
      if (skipping && bmin == bmax) {
        if (tid == 0) sc_prefix |= bmin << shift;
        mask |= 0xFFu << shift;
        __syncthreads();
        continue;
      }
      skipping = false;

      for (int b = tid; b < NW * HSTRIDE; b += NTHR) shm.sel.histw[b] = 0u;
      __syncthreads();
      const unsigned int pref = sc_prefix;
      for (int p = tid; p < P_N; p += NTHR) {
        unsigned int k  = shm.sel.skey[p];
        bool act        = ((k & mask) == pref);
        unsigned int bk = (k >> shift) & 255u;
        // leader-aggregated update: up to 3 distinct buckets handled with
        // one atomic each (clustered MSB passes); remainder per-lane.
        unsigned long long actm = __ballot(act);
        #pragma unroll
        for (int it = 0; it < 3; ++it) {
          if (!actm) break;                                  // wave-uniform
          int ldr = __ffsll((unsigned long long)actm) - 1;
          unsigned int bl = __shfl(bk, ldr, 64);
          unsigned long long mm = __ballot(act && (bk == bl));
          if (act && (lane == ldr))
            atomicAdd(&shm.sel.histw[wave * HSTRIDE + bl], (unsigned)__popcll(mm));
          if (act && (bk == bl)) act = false;
          actm &= ~mm;
        }
        if (act) atomicAdd(&shm.sel.histw[wave * HSTRIDE + bk], 1u);
      }
      __syncthreads();
      // fold NW slices into flat [0..255]
      if (tid < 256) {
        unsigned int tot = 0;
        #pragma unroll
        for (int w = 0; w < NW; ++w) tot += shm.sel.histw[w * HSTRIDE + tid];
        shm.sel.histw[tid] = tot;
      }
      __syncthreads();
      // wave 0: 256-bucket prefix scan (4/lane) + rank search
      if (tid < 64) {
        unsigned h0 = shm.sel.histw[tid * 4 + 0], h1 = shm.sel.histw[tid * 4 + 1];
        unsigned h2 = shm.sel.histw[tid * 4 + 2], h3 = shm.sel.histw[tid * 4 + 3];
        unsigned s1 = h0 + h1, s2 = s1 + h2, s3 = s2 + h3;
        unsigned tot = s3;
        #pragma unroll
        for (int d = 1; d < 64; d <<= 1) {
          unsigned o = __shfl_up(tot, (unsigned)d, 64);
          if (tid >= d) tot += o;
        }
        unsigned base = tot - s3;
        unsigned rr = (unsigned)sc_r;       // all lanes read BEFORE any write
        if (rr >= base && rr < base + s3) { // exactly one lane true
          int bsel; unsigned lo;
          if (rr < base + h0)      { bsel = 0; lo = base; }
          else if (rr < base + s1) { bsel = 1; lo = base + h0; }
          else if (rr < base + s2) { bsel = 2; lo = base + s1; }
          else                     { bsel = 3; lo = base + s2; }
          sc_prefix |= (unsigned)(tid * 4 + bsel) << shift;
          sc_r = (int)(rr - lo);
        }
      }
      mask |= 0xFFu << shift;
      __syncthreads();
    }

    const unsigned int tk = sc_prefix;
    const int needeq = sc_r + 1;

    // compaction: strict-less ballot-aggregated; equals buffered for tie-break
    for (int p = tid; p < P_N; p += NTHR) {
      unsigned int k = shm.sel.skey[p];
      const bool lt = (k < tk);
      unsigned long long m = __ballot(lt);
      int base = 0;
      if (lane == 0) base = atomicAdd(&sc_cntlt, (int)__popcll(m));
      base = __shfl(base, 0, 64);
      if (lt) {
        int pos = base + (int)__popcll(m & ((1ull << lane) - 1ull));
        elite_idx[pos]     = p;
        shm.sel.elite_d[pos] = __uint_as_float(k);
      } else if (k == tk) {
        int ep = atomicAdd(&sc_cnteq, 1);
        if (ep < 256) shm.sel.eqbuf[ep] = p;
      }
    }
    __syncthreads();
    if (tid == 0) {
      int cl = sc_cntlt;
      int ce = sc_cnteq; if (ce > 256) ce = 256;
      for (int rsel = 0; rsel < needeq; ++rsel) {
        int best = 0x7FFFFFFF, bi = 0;
        for (int m = 0; m < ce; ++m) {
          int v = shm.sel.eqbuf[m];
          if (v < best) { best = v; bi = m; }
        }
        shm.sel.eqbuf[bi] = 0x7FFFFFFF;
        elite_idx[cl + rsel]     = best;
        shm.sel.elite_d[cl + rsel] = __uint_as_float(tk);
      }
    }
    __syncthreads();

    // softmax weights
    const float minf = __uint_as_float(sc_minkey);
    float s = (tid < K_N) ? expf(TEMP_C * (minf - shm.sel.elite_d[tid])) : 0.0f;
    float t1 = s;
    #pragma unroll
    for (int d = 32; d > 0; d >>= 1) t1 += __shfl_xor(t1, (unsigned)d, 64);
    if (lane == 0) shm.sel.wsum[wave] = t1;
    __syncthreads();
    if (tid == 0) {
      float acc = 0.0f;
      #pragma unroll
      for (int w = 0; w < NW; ++w) acc += shm.sel.wsum[w];
      sS = acc;
    }
    __syncthreads();
    const float S = sS;
    const float wn = (tid < K_N) ? (s / S) : 0.0f;
    float t2 = wn;
    #pragma unroll
    for (int d = 32; d > 0; d >>= 1) t2 += __shfl_xor(t2, (unsigned)d, 64);
    if (lane == 0) shm.sel.wsum[wave] = t2;
    __syncthreads();
    if (tid == 0) {
      float acc = 0.0f;
      #pragma unroll
      for (int w = 0; w < NW; ++w) acc += shm.sel.wsum[w];
      sS2 = acc;
    }
    __syncthreads();
    if (tid < K_N) elite_wn[tid] = wn;
    if (tid == 0) meta[0] = sS2;

    // release elites, then flip ALL tokens to MAGIC_B
    __threadfence();
    __syncthreads();
    if (tid < NBLK)
      __hip_atomic_store(&done[tid], MAGIC_B, __ATOMIC_RELEASE, SCOPE_AGT);
  }

  // ========== phase 3: stats (blocks 0..127, t = bid) ==========
  if (bid < T_N) {
    if (tid == 0) {
      while (__hip_atomic_load(&done[bid], __ATOMIC_ACQUIRE, SCOPE_AGT) != MAGIC_B)
        __builtin_amdgcn_s_sleep(8);
    }
    __syncthreads();
    __threadfence();   // acquire before reading elite arrays

    const int t  = bid;
    const int a  = tid & 31;
    const int er = tid >> 5;   // 0..15

    for (int e = tid; e < K_N; e += NTHR) {
      shm.st.sidx[e] = __hip_atomic_load(&elite_idx[e], __ATOMIC_RELAXED, SCOPE_AGT);
      shm.st.swn[e]  = __hip_atomic_load(&elite_wn[e],  __ATOMIC_RELAXED, SCOPE_AGT);
    }
    float ssum_l = __hip_atomic_load(&meta[0], __ATOMIC_RELAXED, SCOPE_AGT);
    __syncthreads();

    const float mn = means[t * A_N + a];
    const float sd = stds[t * A_N + a];
    const float* nrow = noise + (size_t)t * P_N * A_N;

    float M = 0.0f, Q = 0.0f;
    for (int e = er; e < K_N; e += 16) {
      const int idx = shm.st.sidx[e];
      const float w = shm.st.swn[e];
      float x = mn + sd * nrow[idx * A_N + a];
      x = fminf(1.0f, fmaxf(-1.0f, x));
      M += w * x;
      Q += w * x * x;
    }
    shm.st.sM[er][a] = M; shm.st.sQ[er][a] = Q;
    __syncthreads();

    if (tid < 32) {
      float Ms = 0.0f, Qs = 0.0f;
      #pragma unroll
      for (int r = 0; r < 16; ++r) { Ms += shm.st.sM[r][a]; Qs += shm.st.sQ[r][a]; }
      const float D = ssum_l + 1e-9f;
      const float mu = Ms / D;
      float var = (Qs - 2.0f * mu * Ms + mu * mu * ssum_l) / D;
      float stdv = sqrtf(fmaxf(var, 0.0f));
      stdv = fminf(1.0f, fmaxf(MIN_STD_C, stdv));
      out[t * A_N + a]             = MOM_C * mn + (1.0f - MOM_C) * mu;
      out[T_N * A_N + t * A_N + a] = stdv;
    }
  }
}

// ---------------------------------------------------------------------------
extern "C" void kernel_launch(void* const* d_in, const int* in_sizes, int n_in,
                              void* d_out, int out_size, void* d_ws, size_t ws_size,
                              hipStream_t stream) {
  const float* obs   = (const float*)d_in[0];   // [P, T, T]
  const float* means = (const float*)d_in[1];   // [T, 1, A]
  const float* stds  = (const float*)d_in[2];   // [T, 1, A]
  const float* noise = (const float*)d_in[3];   // [T, P, A]
  float* out = (float*)d_out;                   // [2, T, 1, A]

  float* dists          = (float*)d_ws;              // P floats
  int*   elite_idx      = (int*)(dists + P_N);       // K ints (padded to 512)
  float* elite_wn       = (float*)(elite_idx + 512); // K floats (padded to 512)
  float* meta           = elite_wn + 512;            // [0] = ssum
  unsigned int* done    = (unsigned int*)(meta + 16);// 256 handshake tokens

  fused_kernel<<<NBLK, NTHR, 0, stream>>>(obs, means, stds, noise,
                                          dists, elite_idx, elite_wn, meta,
                                          done, out);
}

// Round 3
// 489.820 us; speedup vs baseline: 1.0901x; 1.0901x over previous
//
#include <hip/hip_runtime.h>
#include <math.h>

#define P_N 4096
#define T_N 128
#define A_N 32
#define K_N 409          // int(4096 * 0.1)
#define TEMP_C 0.5f
#define MOM_C 0.1f
#define MIN_STD_C 0.05f
#define INF_F 1e30f

#define NBLK 256         // grid: 16 particles per block
#define NTHR 512         // 8 waves per block
#define NW   8
#define HSTRIDE 257      // per-wave histogram stride (bank-spread)
#define MAGIC_A 0x9E3779B1u   // "dtw done" token (must differ from poison)
#define MAGIC_B 0xC2B2AE35u   // "select done" token
#define SCOPE_AGT __HIP_MEMORY_SCOPE_AGENT

// native vector type (Clang ext_vector) — required by __builtin_nontemporal_load
typedef float vfloat4 __attribute__((ext_vector_type(4)));

// DPP move: returns src shifted per ctrl; lanes with invalid source get `oldv`.
// ctrl: 0x110+N row_shr:N, 0x142 row_bcast:15, 0x138 wave_shr:1
#define DPPMOV(dst, src, ctrl, oldv)                                          \
  {                                                                           \
    union { float f; int i; } _a, _b, _r;                                     \
    _a.f = (src); _b.f = (oldv);                                              \
    _r.i = __builtin_amdgcn_update_dpp(_b.i, _a.i, (ctrl), 0xF, 0xF, false);  \
    (dst) = _r.f;                                                             \
  }

// LDS is phase-exclusive: select (block 255) vs stats (blocks 0..127).
union Shm {
  struct {                                   // select phase: ~27 KB
    unsigned int skey[P_N];                  // 16 KB
    unsigned int histw[NW * HSTRIDE];        // 8.2 KB per-wave histograms
    float elite_d[K_N];
    int eqbuf[256];
    float wsum[NW];
  } sel;
  struct {                                   // stats phase: ~7.4 KB
    int   sidx[K_N];
    float swn[K_N];
    float sM[16][32];
    float sQ[16][32];
  } st;
};

// ---------------------------------------------------------------------------
// Single fused kernel.
// Phase 1 (all 256 blocks): DTW min-plus DP, 2 particles/wave, DPP scan.
// Handshake (CRITICAL: spin loops use RELAXED loads — an ACQUIRE atomic load
// on gfx950 emits a cache-invalidate EVERY poll iteration; 1000+ spinning
// waves invalidating L1/L2 under the still-streaming DTW blocks collapsed
// HBM throughput 3x in the previous version. Relaxed agent-scope loads are
// coherent point-accesses with no invalidate side effect; the single
// __threadfence() AFTER the wait provides the acquire.)
// Block 255 waits for all 256 MAGIC_A tokens, runs select, flips tokens to
// MAGIC_B (fence once + relaxed stores). Blocks 0..127 wait for MAGIC_B on
// their own word (which they overwrote with MAGIC_A this launch, so a stale
// MAGIC_B from a previous iteration cannot leak through), then run stats.
// Deadlock-free: every wait is on an unconditional write; all 256 blocks
// co-resident (8 waves, 27 KB LDS -> >=1 block/CU).
// ---------------------------------------------------------------------------
__global__ __launch_bounds__(NTHR, 2) void fused_kernel(
    const float* __restrict__ obs, const float* __restrict__ means,
    const float* __restrict__ stds, const float* __restrict__ noise,
    float* __restrict__ dists, int* __restrict__ elite_idx,
    float* __restrict__ elite_wn, float* __restrict__ meta,
    unsigned int* __restrict__ done, float* __restrict__ out) {
  __shared__ Shm shm;
  __shared__ unsigned int sc_prefix, sc_minkey, sc_maxkey;
  __shared__ int sc_r, sc_cntlt, sc_cnteq;
  __shared__ float sS, sS2;

  const int bid  = blockIdx.x;
  const int tid  = threadIdx.x;
  const int wave = tid >> 6;
  const int lane = tid & 63;

  // ========== phase 1: DTW (identical math to the verified version) ==========
  {
    const int half = lane >> 5;
    const int l    = lane & 31;
    const int p    = bid * 16 + wave * 2 + half;   // particle id
    const bool is0 = (l == 0);

    const vfloat4* row = (const vfloat4*)(obs + (size_t)p * (T_N * T_N)) + l;

    float P1 = INF_F, P2 = INF_F, P3 = INF_F, P4 = INF_F;
    float p0 = is0 ? 0.0f : INF_F;

    vfloat4 cb[8];
    #pragma unroll
    for (int u = 0; u < 8; ++u) cb[u] = __builtin_nontemporal_load(row + u * 32);

    for (int rb = 0; rb < T_N; rb += 8) {
      const bool pf = (rb + 8 < T_N);
      #pragma unroll
      for (int u = 0; u < 8; ++u) {
        vfloat4 c = cb[u];
        if (pf) cb[u] = __builtin_nontemporal_load(row + (rb + u + 8) * 32);

        float a1 = fminf(P1, p0);
        float a2 = fminf(P2, P1);
        float a3 = fminf(P3, P2);
        float a4 = fminf(P4, P3);

        float B = a1 + c.x;
        B = fminf(B + c.y, a2 + c.y);
        B = fminf(B + c.z, a3 + c.z);
        B = fminf(B + c.w, a4 + c.w);
        float C = (c.x + c.y) + (c.z + c.w);

        float Bp, Cp;
        DPPMOV(Bp, B, 0x111, INF_F); DPPMOV(Cp, C, 0x111, 0.0f);
        B = fminf(Bp + C, B); C = Cp + C;
        DPPMOV(Bp, B, 0x112, INF_F); DPPMOV(Cp, C, 0x112, 0.0f);
        B = fminf(Bp + C, B); C = Cp + C;
        DPPMOV(Bp, B, 0x114, INF_F); DPPMOV(Cp, C, 0x114, 0.0f);
        B = fminf(Bp + C, B); C = Cp + C;
        DPPMOV(Bp, B, 0x118, INF_F); DPPMOV(Cp, C, 0x118, 0.0f);
        B = fminf(Bp + C, B); C = Cp + C;
        DPPMOV(Bp, B, 0x142, INF_F); DPPMOV(Cp, C, 0x142, 0.0f);
        B = fminf(Bp + C, B); C = Cp + C;

        float x;
        DPPMOV(x, B, 0x138, INF_F);
        x = is0 ? INF_F : x;

        float n1 = fminf(a1, x)  + c.x;
        float n2 = fminf(a2, n1) + c.y;
        float n3 = fminf(a3, n2) + c.z;
        float n4 = fminf(a4, n3) + c.w;

        p0 = x; P1 = n1; P2 = n2; P3 = n3; P4 = n4;
      }
    }
    if (l == 31) dists[p] = P4;
  }

  // release: one fence flushes dist stores to the coherence point, then post
  // the token with a RELAXED store (fence+relaxed == release publish, without
  // a per-store buffer_wbl2).
  __threadfence();
  __syncthreads();
  if (tid == 0)
    __hip_atomic_store(&done[bid], MAGIC_A, __ATOMIC_RELAXED, SCOPE_AGT);

  // ========== phase 2: select (block NBLK-1 only) ==========
  if (bid == NBLK - 1) {
    if (tid < NBLK) {
      // RELAXED spin: no per-iteration cache invalidate (see header comment)
      while (__hip_atomic_load(&done[tid], __ATOMIC_RELAXED, SCOPE_AGT) != MAGIC_A)
        __builtin_amdgcn_s_sleep(8);
    }
    __syncthreads();
    __threadfence();   // single acquire: invalidate caches before reading dists

    if (tid == 0) { sc_minkey = 0xFFFFFFFFu; sc_maxkey = 0u;
                    sc_cntlt = 0; sc_cnteq = 0; sc_prefix = 0u; sc_r = K_N - 1; }
    __syncthreads();

    // stage keys to LDS + min/max reduce (coherent point loads)
    unsigned int localmin = 0xFFFFFFFFu, localmax = 0u;
    for (int p = tid; p < P_N; p += NTHR) {
      float dv = __hip_atomic_load(&dists[p], __ATOMIC_RELAXED, SCOPE_AGT);
      unsigned int k = __float_as_uint(dv);
      shm.sel.skey[p] = k;
      if (k < localmin) localmin = k;
      if (k > localmax) localmax = k;
    }
    #pragma unroll
    for (int d = 32; d > 0; d >>= 1) {
      unsigned int o = __shfl_xor(localmin, (unsigned)d, 64);
      if (o < localmin) localmin = o;
      unsigned int o2 = __shfl_xor(localmax, (unsigned)d, 64);
      if (o2 > localmax) localmax = o2;
    }
    if (lane == 0) { atomicMin(&sc_minkey, localmin); atomicMax(&sc_maxkey, localmax); }
    __syncthreads();
    const unsigned int mn = sc_minkey, mx = sc_maxkey;

    // radix select, MSB-first. Leading bytes where min==max are shared by
    // ALL keys (integer monotonicity) -> skip those passes outright.
    unsigned int mask = 0;
    bool skipping = true;
    for (int shift = 24; shift >= 0; shift -= 8) {
      const unsigned int bmin = (mn >> shift) & 255u;
      const unsigned int bmax = (mx >> shift) & 255u;
      if (skipping && bmin == bmax) {
        if (tid == 0) sc_prefix |= bmin << shift;
        mask |= 0xFFu << shift;
        __syncthreads();
        continue;
      }
      skipping = false;

      for (int b = tid; b < NW * HSTRIDE; b += NTHR) shm.sel.histw[b] = 0u;
      __syncthreads();
      const unsigned int pref = sc_prefix;
      for (int p = tid; p < P_N; p += NTHR) {
        unsigned int k  = shm.sel.skey[p];
        bool act        = ((k & mask) == pref);
        unsigned int bk = (k >> shift) & 255u;
        // leader-aggregated update: up to 3 distinct buckets handled with
        // one atomic each (clustered MSB passes); remainder per-lane.
        unsigned long long actm = __ballot(act);
        #pragma unroll
        for (int it = 0; it < 3; ++it) {
          if (!actm) break;                                  // wave-uniform
          int ldr = __ffsll((unsigned long long)actm) - 1;
          unsigned int bl = __shfl(bk, ldr, 64);
          unsigned long long mm = __ballot(act && (bk == bl));
          if (act && (lane == ldr))
            atomicAdd(&shm.sel.histw[wave * HSTRIDE + bl], (unsigned)__popcll(mm));
          if (act && (bk == bl)) act = false;
          actm &= ~mm;
        }
        if (act) atomicAdd(&shm.sel.histw[wave * HSTRIDE + bk], 1u);
      }
      __syncthreads();
      // fold NW slices into flat [0..255]
      if (tid < 256) {
        unsigned int tot = 0;
        #pragma unroll
        for (int w = 0; w < NW; ++w) tot += shm.sel.histw[w * HSTRIDE + tid];
        shm.sel.histw[tid] = tot;
      }
      __syncthreads();
      // wave 0: 256-bucket prefix scan (4/lane) + rank search
      if (tid < 64) {
        unsigned h0 = shm.sel.histw[tid * 4 + 0], h1 = shm.sel.histw[tid * 4 + 1];
        unsigned h2 = shm.sel.histw[tid * 4 + 2], h3 = shm.sel.histw[tid * 4 + 3];
        unsigned s1 = h0 + h1, s2 = s1 + h2, s3 = s2 + h3;
        unsigned tot = s3;
        #pragma unroll
        for (int d = 1; d < 64; d <<= 1) {
          unsigned o = __shfl_up(tot, (unsigned)d, 64);
          if (tid >= d) tot += o;
        }
        unsigned base = tot - s3;
        unsigned rr = (unsigned)sc_r;       // all lanes read BEFORE any write
        if (rr >= base && rr < base + s3) { // exactly one lane true
          int bsel; unsigned lo;
          if (rr < base + h0)      { bsel = 0; lo = base; }
          else if (rr < base + s1) { bsel = 1; lo = base + h0; }
          else if (rr < base + s2) { bsel = 2; lo = base + s1; }
          else                     { bsel = 3; lo = base + s2; }
          sc_prefix |= (unsigned)(tid * 4 + bsel) << shift;
          sc_r = (int)(rr - lo);
        }
      }
      mask |= 0xFFu << shift;
      __syncthreads();
    }

    const unsigned int tk = sc_prefix;
    const int needeq = sc_r + 1;

    // compaction: strict-less ballot-aggregated; equals buffered for tie-break
    for (int p = tid; p < P_N; p += NTHR) {
      unsigned int k = shm.sel.skey[p];
      const bool lt = (k < tk);
      unsigned long long m = __ballot(lt);
      int base = 0;
      if (lane == 0) base = atomicAdd(&sc_cntlt, (int)__popcll(m));
      base = __shfl(base, 0, 64);
      if (lt) {
        int pos = base + (int)__popcll(m & ((1ull << lane) - 1ull));
        elite_idx[pos]       = p;
        shm.sel.elite_d[pos] = __uint_as_float(k);
      } else if (k == tk) {
        int ep = atomicAdd(&sc_cnteq, 1);
        if (ep < 256) shm.sel.eqbuf[ep] = p;
      }
    }
    __syncthreads();
    if (tid == 0) {
      int cl = sc_cntlt;
      int ce = sc_cnteq; if (ce > 256) ce = 256;
      for (int rsel = 0; rsel < needeq; ++rsel) {
        int best = 0x7FFFFFFF, bi = 0;
        for (int m = 0; m < ce; ++m) {
          int v = shm.sel.eqbuf[m];
          if (v < best) { best = v; bi = m; }
        }
        shm.sel.eqbuf[bi] = 0x7FFFFFFF;
        elite_idx[cl + rsel]       = best;
        shm.sel.elite_d[cl + rsel] = __uint_as_float(tk);
      }
    }
    __syncthreads();

    // softmax weights
    const float minf = __uint_as_float(sc_minkey);
    float s = (tid < K_N) ? expf(TEMP_C * (minf - shm.sel.elite_d[tid])) : 0.0f;
    float t1 = s;
    #pragma unroll
    for (int d = 32; d > 0; d >>= 1) t1 += __shfl_xor(t1, (unsigned)d, 64);
    if (lane == 0) shm.sel.wsum[wave] = t1;
    __syncthreads();
    if (tid == 0) {
      float acc = 0.0f;
      #pragma unroll
      for (int w = 0; w < NW; ++w) acc += shm.sel.wsum[w];
      sS = acc;
    }
    __syncthreads();
    const float S = sS;
    const float wn = (tid < K_N) ? (s / S) : 0.0f;
    float t2 = wn;
    #pragma unroll
    for (int d = 32; d > 0; d >>= 1) t2 += __shfl_xor(t2, (unsigned)d, 64);
    if (lane == 0) shm.sel.wsum[wave] = t2;
    __syncthreads();
    if (tid == 0) {
      float acc = 0.0f;
      #pragma unroll
      for (int w = 0; w < NW; ++w) acc += shm.sel.wsum[w];
      sS2 = acc;
    }
    __syncthreads();
    if (tid < K_N) elite_wn[tid] = wn;
    if (tid == 0) meta[0] = sS2;

    // publish elites: one fence, then RELAXED token flips
    __threadfence();
    __syncthreads();
    if (tid < NBLK)
      __hip_atomic_store(&done[tid], MAGIC_B, __ATOMIC_RELAXED, SCOPE_AGT);
  }

  // ========== phase 3: stats (blocks 0..127, t = bid) ==========
  if (bid < T_N) {
    if (tid == 0) {
      // RELAXED spin (no invalidate storm); acquire comes from the fence below
      while (__hip_atomic_load(&done[bid], __ATOMIC_RELAXED, SCOPE_AGT) != MAGIC_B)
        __builtin_amdgcn_s_sleep(8);
    }
    __syncthreads();
    __threadfence();   // single acquire before reading elite arrays

    const int t  = bid;
    const int a  = tid & 31;
    const int er = tid >> 5;   // 0..15

    for (int e = tid; e < K_N; e += NTHR) {
      shm.st.sidx[e] = __hip_atomic_load(&elite_idx[e], __ATOMIC_RELAXED, SCOPE_AGT);
      shm.st.swn[e]  = __hip_atomic_load(&elite_wn[e],  __ATOMIC_RELAXED, SCOPE_AGT);
    }
    float ssum_l = __hip_atomic_load(&meta[0], __ATOMIC_RELAXED, SCOPE_AGT);
    __syncthreads();

    const float mn = means[t * A_N + a];
    const float sd = stds[t * A_N + a];
    const float* nrow = noise + (size_t)t * P_N * A_N;

    float M = 0.0f, Q = 0.0f;
    for (int e = er; e < K_N; e += 16) {
      const int idx = shm.st.sidx[e];
      const float w = shm.st.swn[e];
      float x = mn + sd * nrow[idx * A_N + a];
      x = fminf(1.0f, fmaxf(-1.0f, x));
      M += w * x;
      Q += w * x * x;
    }
    shm.st.sM[er][a] = M; shm.st.sQ[er][a] = Q;
    __syncthreads();

    if (tid < 32) {
      float Ms = 0.0f, Qs = 0.0f;
      #pragma unroll
      for (int r = 0; r < 16; ++r) { Ms += shm.st.sM[r][a]; Qs += shm.st.sQ[r][a]; }
      const float D = ssum_l + 1e-9f;
      const float mu = Ms / D;
      float var = (Qs - 2.0f * mu * Ms + mu * mu * ssum_l) / D;
      float stdv = sqrtf(fmaxf(var, 0.0f));
      stdv = fminf(1.0f, fmaxf(MIN_STD_C, stdv));
      out[t * A_N + a]             = MOM_C * mn + (1.0f - MOM_C) * mu;
      out[T_N * A_N + t * A_N + a] = stdv;
    }
  }
}

// ---------------------------------------------------------------------------
extern "C" void kernel_launch(void* const* d_in, const int* in_sizes, int n_in,
                              void* d_out, int out_size, void* d_ws, size_t ws_size,
                              hipStream_t stream) {
  const float* obs   = (const float*)d_in[0];   // [P, T, T]
  const float* means = (const float*)d_in[1];   // [T, 1, A]
  const float* stds  = (const float*)d_in[2];   // [T, 1, A]
  const float* noise = (const float*)d_in[3];   // [T, P, A]
  float* out = (float*)d_out;                   // [2, T, 1, A]

  float* dists          = (float*)d_ws;              // P floats
  int*   elite_idx      = (int*)(dists + P_N);       // K ints (padded to 512)
  float* elite_wn       = (float*)(elite_idx + 512); // K floats (padded to 512)
  float* meta           = elite_wn + 512;            // [0] = ssum
  unsigned int* done    = (unsigned int*)(meta + 16);// 256 handshake tokens

  fused_kernel<<<NBLK, NTHR, 0, stream>>>(obs, means, stds, noise,
                                          dists, elite_idx, elite_wn, meta,
                                          done, out);
}

// Round 6
// 399.946 us; speedup vs baseline: 1.3350x; 1.2247x over previous
//
#include <hip/hip_runtime.h>
#include <math.h>

#define P_N 4096
#define T_N 128
#define A_N 32
#define K_N 409          // int(4096 * 0.1)
#define TEMP_C 0.5f
#define MOM_C 0.1f
#define MIN_STD_C 0.05f
#define INF_F 1e30f

// native vector type (Clang ext_vector) — required by __builtin_nontemporal_load
typedef float vfloat4 __attribute__((ext_vector_type(4)));

// DPP move: returns src shifted per ctrl; lanes with invalid source get `oldv`.
// ctrl: 0x110+N row_shr:N, 0x142 row_bcast:15, 0x138 wave_shr:1
#define DPPMOV(dst, src, ctrl, oldv)                                          \
  {                                                                           \
    union { float f; int i; } _a, _b, _r;                                     \
    _a.f = (src); _b.f = (oldv);                                              \
    _r.i = __builtin_amdgcn_update_dpp(_b.i, _a.i, (ctrl), 0xF, 0xF, false);  \
    (dst) = _r.f;                                                             \
  }

// ---------------------------------------------------------------------------
// Kernel 1: DTW min-plus DP. One wave = 2 particles (one per 32-lane half).
// Lane l (0..31 within half) owns DP columns 4l+1..4l+4 (1-indexed).
// Row recurrence new[j] = min(min(prev[j],prev[j-1]), new[j-1]) + c[j] is an
// affine (min,+) map x -> min(x + C, B); per-lane composites are combined
// with a 32-lane inclusive scan done entirely in DPP (VALU latency, no LDS).
// BW-bound at ~43 µs floor (268 MB read-once): nontemporal loads, depth-8
// software prefetch (unroll-by-8 rotation, no register shuffling), and no
// redundant clamped tail loads.
// NOTE (round-2/3 lesson): do NOT fuse this with later phases — inside a
// phase-fused mega-kernel the same loop ran 2-3x slower.
// ---------------------------------------------------------------------------
__global__ __launch_bounds__(256) void dtw_kernel(const float* __restrict__ obs,
                                                  float* __restrict__ dists) {
  const int tid  = threadIdx.x;
  const int wave = tid >> 6;
  const int lane = tid & 63;
  const int half = lane >> 5;
  const int l    = lane & 31;
  const int p    = blockIdx.x * 8 + wave * 2 + half;   // particle id
  const bool is0 = (l == 0);

  const vfloat4* row = (const vfloat4*)(obs + (size_t)p * (T_N * T_N)) + l;

  // prev-row state: P1..P4 = D[i][4l+1..4l+4], p0 = D[i][4l]
  float P1 = INF_F, P2 = INF_F, P3 = INF_F, P4 = INF_F;
  float p0 = is0 ? 0.0f : INF_F;   // D[0][0] = 0, rest of row 0 = INF

  // software prefetch, depth 8, nontemporal (read-once). 128 % 8 == 0 so the
  // unroll-by-8 rotation has compile-time buffer indices (registers, no movs).
  vfloat4 cb[8];
  #pragma unroll
  for (int u = 0; u < 8; ++u) cb[u] = __builtin_nontemporal_load(row + u * 32);

  for (int rb = 0; rb < T_N; rb += 8) {
    const bool pf = (rb + 8 < T_N);   // wave-uniform; false only on last iter
    #pragma unroll
    for (int u = 0; u < 8; ++u) {
      vfloat4 c = cb[u];
      if (pf) cb[u] = __builtin_nontemporal_load(row + (rb + u + 8) * 32);

      // a[j] = min(prev[j], prev[j-1])
      float a1 = fminf(P1, p0);
      float a2 = fminf(P2, P1);
      float a3 = fminf(P3, P2);
      float a4 = fminf(P4, P3);

      // per-lane composite over 4 columns: f(x) = min(x + C, B)
      float B = a1 + c.x;
      B = fminf(B + c.y, a2 + c.y);
      B = fminf(B + c.z, a3 + c.z);
      B = fminf(B + c.w, a4 + c.w);
      float C = (c.x + c.y) + (c.z + c.w);

      // inclusive 32-lane scan via DPP: combine earlier segment (Bp,Cp) into
      // later (B,C):  B = min(Bp + C, B);  C = Cp + C.
      // Identity injection: Bp=INF, Cp=0 for lanes with no source.
      float Bp, Cp;
      DPPMOV(Bp, B, 0x111, INF_F); DPPMOV(Cp, C, 0x111, 0.0f);  // row_shr:1
      B = fminf(Bp + C, B); C = Cp + C;
      DPPMOV(Bp, B, 0x112, INF_F); DPPMOV(Cp, C, 0x112, 0.0f);  // row_shr:2
      B = fminf(Bp + C, B); C = Cp + C;
      DPPMOV(Bp, B, 0x114, INF_F); DPPMOV(Cp, C, 0x114, 0.0f);  // row_shr:4
      B = fminf(Bp + C, B); C = Cp + C;
      DPPMOV(Bp, B, 0x118, INF_F); DPPMOV(Cp, C, 0x118, 0.0f);  // row_shr:8
      B = fminf(Bp + C, B); C = Cp + C;
      DPPMOV(Bp, B, 0x142, INF_F); DPPMOV(Cp, C, 0x142, 0.0f);  // row_bcast:15
      B = fminf(Bp + C, B); C = Cp + C;

      // carry-in for lane l: new[4l] = B_incl(l-1); lane 0 of each half -> INF
      float x;
      DPPMOV(x, B, 0x138, INF_F);   // wave_shr:1
      x = is0 ? INF_F : x;          // fixes lane 0 AND lane 32 (cross-half leak)

      // apply: sequential within lane (kept bit-identical to prior version)
      float n1 = fminf(a1, x)  + c.x;
      float n2 = fminf(a2, n1) + c.y;
      float n3 = fminf(a3, n2) + c.z;
      float n4 = fminf(a4, n3) + c.w;

      p0 = x; P1 = n1; P2 = n2; P3 = n3; P4 = n4;
    }
  }

  if (l == 31) dists[p] = P4;   // D[T][T]
}

// ---------------------------------------------------------------------------
// Kernel 2: exact top-K selection (radix-select on fp32 bit patterns, which
// are monotone for non-negative dists), index-ordered tie-break to match
// lax.top_k, then softmax weights. Single block, 1024 threads.
// Per-wave private histograms kill same-bucket LDS-atomic serialization
// (dists cluster into 2-3 exponent buckets in the MSB passes).
// Histogram slices padded to stride 257: 256 % 32 == 0 put all 16 wave
// slices on the SAME LDS bank, serializing cross-wave atomics in the
// clustered MSB pass; +1 word spreads slices across banks.
// ---------------------------------------------------------------------------
#define HSTRIDE 257

__global__ __launch_bounds__(1024) void select_kernel(const float* __restrict__ dists,
                                                      int* __restrict__ elite_idx,
                                                      float* __restrict__ elite_wn,
                                                      float* __restrict__ meta) {
  __shared__ alignas(16) unsigned int skey[P_N];    // 16 KB
  __shared__ unsigned int histw[16 * HSTRIDE];      // ~16 KB: per-wave histograms
  __shared__ float elite_d[K_N];
  __shared__ int eqbuf[256];
  __shared__ float wsum[16];
  __shared__ unsigned int sc_prefix, sc_minkey;
  __shared__ int sc_r, sc_cntlt, sc_cnteq;
  __shared__ float sS, sS2;

  const int tid  = threadIdx.x;
  const int wid  = tid >> 6;
  const int lane = tid & 63;

  // load keys to LDS (vectorized: one float4 per thread) + min-reduce
  const float4 d4 = ((const float4*)dists)[tid];
  const unsigned int ka = __float_as_uint(d4.x);
  const unsigned int kb = __float_as_uint(d4.y);
  const unsigned int kc = __float_as_uint(d4.z);
  const unsigned int kd = __float_as_uint(d4.w);
  ((uint4*)skey)[tid] = make_uint4(ka, kb, kc, kd);
  unsigned int localmin = ka;
  if (kb < localmin) localmin = kb;
  if (kc < localmin) localmin = kc;
  if (kd < localmin) localmin = kd;
  #pragma unroll
  for (int d = 32; d > 0; d >>= 1) {
    unsigned int o = __shfl_xor(localmin, (unsigned)d, 64);
    if (o < localmin) localmin = o;
  }
  if (tid == 0) { sc_minkey = 0xFFFFFFFFu; sc_cntlt = 0; sc_cnteq = 0;
                  sc_prefix = 0; sc_r = K_N - 1; }
  __syncthreads();
  if (lane == 0) atomicMin(&sc_minkey, localmin);
  __syncthreads();

  // radix select: 4 passes, msb first
  unsigned int mask = 0;
  for (int shift = 24; shift >= 0; shift -= 8) {
    for (int b = tid; b < 16 * HSTRIDE; b += 1024) histw[b] = 0;
    __syncthreads();
    unsigned int pref = sc_prefix;
    for (int p = tid; p < P_N; p += 1024) {
      unsigned int k = skey[p];
      if ((k & mask) == pref)
        atomicAdd(&histw[wid * HSTRIDE + ((k >> shift) & 255u)], 1u);
    }
    __syncthreads();
    // fold 16 slices: thread b (<256) sums its bucket into flat [0..255]
    if (tid < 256) {
      unsigned tot = 0;
      #pragma unroll
      for (int w = 0; w < 16; ++w) tot += histw[w * HSTRIDE + tid];
      histw[tid] = tot;
    }
    __syncthreads();
    // wave 0: parallel 256-bucket prefix scan (4 buckets/lane) + rank search
    if (tid < 64) {
      unsigned h0 = histw[tid * 4 + 0], h1 = histw[tid * 4 + 1];
      unsigned h2 = histw[tid * 4 + 2], h3 = histw[tid * 4 + 3];
      unsigned s1 = h0 + h1, s2 = s1 + h2, s3 = s2 + h3;
      unsigned tot = s3;
      #pragma unroll
      for (int d = 1; d < 64; d <<= 1) {
        unsigned o = __shfl_up(tot, (unsigned)d, 64);
        if (tid >= d) tot += o;
      }
      unsigned base = tot - s3;            // exclusive start of bucket tid*4
      unsigned rr = (unsigned)sc_r;        // all lanes read BEFORE any write
      if (rr >= base && rr < base + s3) {  // exactly one lane true
        int bsel; unsigned lo;
        if (rr < base + h0)      { bsel = 0; lo = base; }
        else if (rr < base + s1) { bsel = 1; lo = base + h0; }
        else if (rr < base + s2) { bsel = 2; lo = base + s1; }
        else                     { bsel = 3; lo = base + s2; }
        sc_prefix |= (unsigned)(tid * 4 + bsel) << shift;
        sc_r = (int)(rr - lo);
      }
    }
    mask |= 0xFFu << shift;
    __syncthreads();
  }

  const unsigned int tk = sc_prefix;     // key of K-th smallest (rank K-1)
  const int needeq = sc_r + 1;           // how many ==tk entries to include

  // compaction: strict-less, ballot-aggregated (order is irrelevant
  // downstream; only membership matters). Equals buffered for tie-break.
  for (int p = tid; p < P_N; p += 1024) {
    unsigned int k = skey[p];
    const bool lt = (k < tk);
    unsigned long long m = __ballot(lt);
    int base = 0;
    if (lane == 0) base = atomicAdd(&sc_cntlt, (int)__popcll(m));
    base = __shfl(base, 0, 64);
    if (lt) {
      int pos = base + (int)__popcll(m & ((1ull << lane) - 1ull));
      elite_idx[pos] = p;
      elite_d[pos]   = __uint_as_float(k);
    } else if (k == tk) {
      int ep = atomicAdd(&sc_cnteq, 1);
      if (ep < 256) eqbuf[ep] = p;
    }
  }
  __syncthreads();
  if (tid == 0) {
    // take the `needeq` lowest indices among equals (lax.top_k tie-break)
    int cl = sc_cntlt;
    int ce = sc_cnteq; if (ce > 256) ce = 256;
    for (int rsel = 0; rsel < needeq; ++rsel) {
      int best = 0x7FFFFFFF, bi = 0;
      for (int m = 0; m < ce; ++m) {
        int v = eqbuf[m];
        if (v < best) { best = v; bi = m; }
      }
      eqbuf[bi] = 0x7FFFFFFF;
      elite_idx[cl + rsel] = best;
      elite_d[cl + rsel]   = __uint_as_float(tk);
    }
  }
  __syncthreads();

  // softmax weights: s_e = exp(TEMP*(min - d_e)); wn = s/S; ssum = sum(wn)
  const float minf = __uint_as_float(sc_minkey);
  float s = (tid < K_N) ? expf(TEMP_C * (minf - elite_d[tid])) : 0.0f;
  // wave-level sum then 16-partial fold
  float t1 = s;
  #pragma unroll
  for (int d = 32; d > 0; d >>= 1) t1 += __shfl_xor(t1, (unsigned)d, 64);
  if (lane == 0) wsum[wid] = t1;
  __syncthreads();
  if (tid == 0) {
    float acc = 0.0f;
    #pragma unroll
    for (int w = 0; w < 16; ++w) acc += wsum[w];
    sS = acc;
  }
  __syncthreads();
  const float S = sS;
  const float wn = (tid < K_N) ? (s / S) : 0.0f;
  float t2 = wn;
  #pragma unroll
  for (int d = 32; d > 0; d >>= 1) t2 += __shfl_xor(t2, (unsigned)d, 64);
  if (lane == 0) wsum[wid] = t2;
  __syncthreads();
  if (tid == 0) {
    float acc = 0.0f;
    #pragma unroll
    for (int w = 0; w < 16; ++w) acc += wsum[w];
    sS2 = acc;
  }
  __syncthreads();
  if (tid < K_N) elite_wn[tid] = wn;
  if (tid == 0) meta[0] = sS2;   // ssum (≈1, computed like reference)
}

// ---------------------------------------------------------------------------
// Kernel 3: per-t weighted mean/std over elite actions (gather only elites).
// Block = 512 threads = 16 elite-lanes x 32 action dims.
// ---------------------------------------------------------------------------
__global__ __launch_bounds__(512) void elite_stats_kernel(
    const float* __restrict__ noise, const float* __restrict__ means,
    const float* __restrict__ stds, const int* __restrict__ elite_idx,
    const float* __restrict__ elite_wn, const float* __restrict__ meta,
    float* __restrict__ out) {
  const int t = blockIdx.x;
  const int tid = threadIdx.x;
  const int a  = tid & 31;
  const int er = tid >> 5;   // 0..15
  __shared__ int   sidx[K_N];
  __shared__ float swn[K_N];
  __shared__ float sM[16][32];
  __shared__ float sQ[16][32];

  for (int e = tid; e < K_N; e += 512) { sidx[e] = elite_idx[e]; swn[e] = elite_wn[e]; }
  __syncthreads();

  const float mn = means[t * A_N + a];
  const float sd = stds[t * A_N + a];
  const float* nrow = noise + (size_t)t * P_N * A_N;

  float M = 0.0f, Q = 0.0f;
  for (int e = er; e < K_N; e += 16) {
    const int idx = sidx[e];
    const float w = swn[e];
    float x = mn + sd * nrow[idx * A_N + a];
    x = fminf(1.0f, fmaxf(-1.0f, x));   // clip(actions, -1, 1)
    M += w * x;
    Q += w * x * x;
  }
  sM[er][a] = M; sQ[er][a] = Q;
  __syncthreads();

  if (tid < 32) {
    float Ms = 0.0f, Qs = 0.0f;
    #pragma unroll
    for (int r = 0; r < 16; ++r) { Ms += sM[r][a]; Qs += sQ[r][a]; }
    const float ssum = meta[0];
    const float D = ssum + 1e-9f;
    const float mu = Ms / D;                                  // _mean
    float var = (Qs - 2.0f * mu * Ms + mu * mu * ssum) / D;   // sum w(x-mu)^2 / D
    float stdv = sqrtf(fmaxf(var, 0.0f));
    stdv = fminf(1.0f, fmaxf(MIN_STD_C, stdv));
    out[t * A_N + a]              = MOM_C * mn + (1.0f - MOM_C) * mu;  // means_new
    out[T_N * A_N + t * A_N + a]  = stdv;                              // _std
  }
}

// ---------------------------------------------------------------------------
extern "C" void kernel_launch(void* const* d_in, const int* in_sizes, int n_in,
                              void* d_out, int out_size, void* d_ws, size_t ws_size,
                              hipStream_t stream) {
  const float* obs   = (const float*)d_in[0];   // [P, T, T]
  const float* means = (const float*)d_in[1];   // [T, 1, A]
  const float* stds  = (const float*)d_in[2];   // [T, 1, A]
  const float* noise = (const float*)d_in[3];   // [T, P, A]
  float* out = (float*)d_out;                   // [2, T, 1, A]

  float* dists     = (float*)d_ws;              // P floats
  int*   elite_idx = (int*)(dists + P_N);       // K ints (padded to 512)
  float* elite_wn  = (float*)(elite_idx + 512); // K floats (padded to 512)
  float* meta      = elite_wn + 512;            // [0] = ssum

  dtw_kernel<<<P_N / 8, 256, 0, stream>>>(obs, dists);
  select_kernel<<<1, 1024, 0, stream>>>(dists, elite_idx, elite_wn, meta);
  elite_stats_kernel<<<T_N, 512, 0, stream>>>(noise, means, stds,
                                              elite_idx, elite_wn, meta, out);
}